// Round 7
// baseline (1650822.266 us; speedup 1.0000x reference)
//
#include <hip/hip_runtime.h>
#include <stdint.h>

typedef _Float16 f16;
typedef f16 f16x2 __attribute__((ext_vector_type(2)));

#define T_LEN 32768
#define HID   512
#define IN_D  1024
#define OUT_D 128
#define NT    512
#define NBLK  4
#define RPB   128        // rows per block
#define SLICE_DW 32768   // 128KB W slice per block, in dwords

__device__ __forceinline__ float dot2f(uint32_t w, uint32_t v, float acc) {
    return __builtin_amdgcn_fdot2(__builtin_bit_cast(f16x2, w),
                                  __builtin_bit_cast(f16x2, v), acc, false);
}
__device__ __forceinline__ float fast_tanh(float z) {
    float e = __expf(2.f * z);
    return 1.f - 2.f * __builtin_amdgcn_rcpf(e + 1.f);
}

// ---------------------------------------------------------------------------
// K0: pack W (fp32 -> f16x2) into 4 row-slices. Slice c: rows [c*128,+128).
// dst4[j*NT + t], j in [0,16): rl=j&1, c8=j>>1; element (j,mm):
//   row = c*128 + 2*(t>>3) + rl,  k0 = (t&7)*64 + c8*8 + mm*2.
// grid 8: bid<4 -> W_ode slice bid; bid>=4 -> W_h slice bid-4.
// ---------------------------------------------------------------------------
__global__ __launch_bounds__(NT) void k_prep(const float* __restrict__ W_ode,
                                             const float* __restrict__ W_h,
                                             uint32_t* __restrict__ ode_prep,
                                             uint32_t* __restrict__ wh_prep) {
    const int bid = blockIdx.x;
    const int c = bid & 3;
    const float* W = (bid >> 2) ? W_h : W_ode;
    uint4* dst = (uint4*)(((bid >> 2) ? wh_prep : ode_prep) + (size_t)c * SLICE_DW);
    const int t = threadIdx.x, rg = t >> 3, kg = t & 7;
    for (int j = 0; j < 16; ++j) {
        const int rl = j & 1, c8 = j >> 1;
        const int row = c * RPB + 2 * rg + rl;
        uint32_t cc[4];
#pragma unroll
        for (int mm = 0; mm < 4; ++mm) {
            const int k0 = kg * 64 + c8 * 8 + mm * 2;
            f16x2 pk;
            pk[0] = (f16)W[row * HID + k0];
            pk[1] = (f16)W[row * HID + k0 + 1];
            cc[mm] = __builtin_bit_cast(uint32_t, pk);
        }
        dst[j * NT + t] = uint4{cc[0], cc[1], cc[2], cc[3]};
    }
}

// ---------------------------------------------------------------------------
// K1: pre[i][j] = W_in @ x_i + b_in + b_h   (fp32 tiled GEMM) — unchanged.
// ---------------------------------------------------------------------------
__global__ __launch_bounds__(512) void k_pre(const float* __restrict__ x,
                                             const float* __restrict__ W_in,
                                             const float* __restrict__ b_in,
                                             const float* __restrict__ b_h,
                                             float* __restrict__ pre32,
                                             uint16_t* __restrict__ pre16,
                                             int preF32) {
    __shared__ float xs[64][34];
    __shared__ float wsh[256][34];
    const int t  = threadIdx.x;
    const int i0 = (blockIdx.x >> 1) * 64;
    const int j0 = (blockIdx.x & 1) * 256;
    const int ti = t >> 5, tj = t & 31;

    float acc[4][8];
#pragma unroll
    for (int a = 0; a < 4; ++a)
#pragma unroll
        for (int b = 0; b < 8; ++b) acc[a][b] = 0.f;

    for (int kb = 0; kb < 32; ++kb) {
        __syncthreads();
        {
            int r = t >> 3, cc = (t & 7) * 4;
            float4 v = *(const float4*)&x[(size_t)(i0 + r) * IN_D + kb * 32 + cc];
            xs[r][cc] = v.x; xs[r][cc + 1] = v.y; xs[r][cc + 2] = v.z; xs[r][cc + 3] = v.w;
        }
        {
            int jr = t >> 1, c0 = (t & 1) * 16;
#pragma unroll
            for (int qd = 0; qd < 4; ++qd) {
                float4 v = *(const float4*)&W_in[(size_t)(j0 + jr) * IN_D + kb * 32 + c0 + qd * 4];
                wsh[jr][c0 + qd * 4]     = v.x; wsh[jr][c0 + qd * 4 + 1] = v.y;
                wsh[jr][c0 + qd * 4 + 2] = v.z; wsh[jr][c0 + qd * 4 + 3] = v.w;
            }
        }
        __syncthreads();
#pragma unroll 4
        for (int k = 0; k < 32; ++k) {
            float xv[4], wv[8];
#pragma unroll
            for (int ii = 0; ii < 4; ++ii) xv[ii] = xs[ti * 4 + ii][k];
#pragma unroll
            for (int jj = 0; jj < 8; ++jj) wv[jj] = wsh[tj + 32 * jj][k];
#pragma unroll
            for (int ii = 0; ii < 4; ++ii)
#pragma unroll
                for (int jj = 0; jj < 8; ++jj)
                    acc[ii][jj] = fmaf(xv[ii], wv[jj], acc[ii][jj]);
        }
    }
#pragma unroll
    for (int ii = 0; ii < 4; ++ii)
#pragma unroll
        for (int jj = 0; jj < 8; ++jj) {
            int ig = i0 + ti * 4 + ii, jg = j0 + tj + 32 * jj;
            float r = acc[ii][jj] + b_in[jg] + b_h[jg];
            if (preF32) pre32[(size_t)ig * HID + jg] = r;
            else        pre16[(size_t)ig * HID + jg] = __builtin_bit_cast(uint16_t, (f16)r);
        }
}

// ---------------------------------------------------------------------------
// K2: sequential scan on 4 CUs (grid=4). Block c owns rows [c*128,+128):
// W_ode slice fully in VGPRs (64 dw/thread), W_h slice fully in LDS (128KB).
// Per matvec: 64 dot2/thread -> 3-shfl reduce -> owner lanes publish their
// 256B v-slice via agent-scope atomics (L3) -> fetch 3 remote slices -> LDS.
// One __syncthreads per matvec. Flags memset to 0 each launch.
// ---------------------------------------------------------------------------
__global__ __launch_bounds__(NT) void k_scan(
    const uint32_t* __restrict__ ode_prep, const uint32_t* __restrict__ wh_prep,
    const float* __restrict__ pre32, const uint16_t* __restrict__ pre16, int preF32,
    const float* __restrict__ tarr, const float* __restrict__ b_ode,
    const float* __restrict__ W_dec, const float* __restrict__ b_dec,
    uint32_t* vx, uint32_t* vflag,
    float* __restrict__ out)
{
    __shared__ uint4 whlds[16 * NT];                  // 128KB: W_h slice
    __shared__ __align__(16) uint16_t vbuf[2][576];   // f16 v, 8 groups x 144B

    const int c  = blockIdx.x;
    const int t  = threadIdx.x;
    const int rg = t >> 3, kg = t & 7;
    const int row_glob = c * RPB + 2 * rg + (kg & 1);
    const uint4* o4 = (const uint4*)(ode_prep + (size_t)c * SLICE_DW);
    const uint4* h4 = (const uint4*)(wh_prep  + (size_t)c * SLICE_DW);

    uint32_t wreg[64];
#pragma unroll
    for (int j = 0; j < 16; ++j) {
        uint4 w = o4[j * NT + t];
        wreg[4 * j] = w.x; wreg[4 * j + 1] = w.y;
        wreg[4 * j + 2] = w.z; wreg[4 * j + 3] = w.w;
    }
#pragma unroll
    for (int j = 0; j < 16; ++j)
        whlds[j * NT + t] = h4[j * NT + t];

    const float bo = b_ode[row_glob];

    // fetch-task assignment: waves 1..6, lanes kg==2, 8 tasks/wave = 48 tasks
    const int wv = t >> 6;
    const bool is_fetcher = (wv >= 1 && wv <= 6 && kg == 2);
    int fb = 0, fp = 0;
    if (is_fetcher) {
        int task = (wv - 1) * 8 + (rg & 7);     // 0..47
        fb = (c + 1 + (task >> 4)) & 3;         // remote block
        fp = task & 15;                         // 16B piece of its 256B slice
    }

    int cur = 1;
    uint32_t m = 0;

    auto reduceZ = [&](float a0, float a1) -> float {
        float mine = (kg & 1) ? a1 : a0;
        float oth  = (kg & 1) ? a0 : a1;
        float b = mine + __shfl_xor(oth, 1);
        b += __shfl_xor(b, 2);
        b += __shfl_xor(b, 4);
        return b;                                // z for row 2rg+(kg&1), all lanes
    };

    auto mv_ode = [&]() -> float {
        float a0 = 0.f, a1 = 0.f;
        const char* vb = (const char*)&vbuf[cur][0] + kg * 144;
#pragma unroll
        for (int c8 = 0; c8 < 8; ++c8) {
            const uint4 vv = *(const uint4*)(vb + c8 * 16);
            const int j0 = (c8 * 2) * 4, j1 = (c8 * 2 + 1) * 4;
            a0 = dot2f(wreg[j0],     vv.x, a0);
            a0 = dot2f(wreg[j0 + 1], vv.y, a0);
            a0 = dot2f(wreg[j0 + 2], vv.z, a0);
            a0 = dot2f(wreg[j0 + 3], vv.w, a0);
            a1 = dot2f(wreg[j1],     vv.x, a1);
            a1 = dot2f(wreg[j1 + 1], vv.y, a1);
            a1 = dot2f(wreg[j1 + 2], vv.z, a1);
            a1 = dot2f(wreg[j1 + 3], vv.w, a1);
        }
        return reduceZ(a0, a1);
    };

    auto mv_wh = [&]() -> float {
        float a0 = 0.f, a1 = 0.f;
        const char* vb = (const char*)&vbuf[cur][0] + kg * 144;
#pragma unroll
        for (int c8 = 0; c8 < 8; ++c8) {
            const uint4 vv = *(const uint4*)(vb + c8 * 16);
            const uint4 w0 = whlds[(c8 * 2) * NT + t];
            const uint4 w1 = whlds[(c8 * 2 + 1) * NT + t];
            a0 = dot2f(w0.x, vv.x, a0); a0 = dot2f(w0.y, vv.y, a0);
            a0 = dot2f(w0.z, vv.z, a0); a0 = dot2f(w0.w, vv.w, a0);
            a1 = dot2f(w1.x, vv.x, a1); a1 = dot2f(w1.y, vv.y, a1);
            a1 = dot2f(w1.z, vv.z, a1); a1 = dot2f(w1.w, vv.w, a1);
        }
        return reduceZ(a0, a1);
    };

    // publish own v-slice + fetch remote slices; one barrier per matvec
    auto pushx = [&](float n) {
        ++m;
        const int nxt = cur ^ 1;
        const uint16_t nb = __builtin_bit_cast(uint16_t, (f16)n);
        if (kg < 2)
            vbuf[nxt][(row_glob >> 6) * 72 + (row_glob & 63)] = nb;
        const uint32_t ob = (uint32_t)(uint16_t)__shfl_xor((int)nb, 1);
        if (kg == 0) {
            uint32_t dw = (uint32_t)nb | (ob << 16);   // rows (2rg, 2rg+1)
            __hip_atomic_store(&vx[(m & 1) * 256 + c * 64 + rg], dw,
                               __ATOMIC_RELAXED, __HIP_MEMORY_SCOPE_AGENT);
        }
        if (kg == 0 && (rg & 7) == 0)
            __hip_atomic_store(&vflag[(c * 8 + (rg >> 3)) * 16], m,
                               __ATOMIC_RELEASE, __HIP_MEMORY_SCOPE_AGENT);
        if (is_fetcher) {
            uint32_t* fa = &vflag[(fb * 8 + (fp >> 1)) * 16];
            while (__hip_atomic_load(fa, __ATOMIC_RELAXED,
                                     __HIP_MEMORY_SCOPE_AGENT) < m) {}
            (void)__hip_atomic_load(fa, __ATOMIC_ACQUIRE, __HIP_MEMORY_SCOPE_AGENT);
            uint32_t* src = &vx[(m & 1) * 256 + fb * 64 + 4 * fp];
            uint32_t d0 = __hip_atomic_load(src,     __ATOMIC_RELAXED, __HIP_MEMORY_SCOPE_AGENT);
            uint32_t d1 = __hip_atomic_load(src + 1, __ATOMIC_RELAXED, __HIP_MEMORY_SCOPE_AGENT);
            uint32_t d2 = __hip_atomic_load(src + 2, __ATOMIC_RELAXED, __HIP_MEMORY_SCOPE_AGENT);
            uint32_t d3 = __hip_atomic_load(src + 3, __ATOMIC_RELAXED, __HIP_MEMORY_SCOPE_AGENT);
            *(uint4*)((char*)&vbuf[nxt][0] + (2 * fb + (fp >> 3)) * 144 + (fp & 7) * 16)
                = uint4{d0, d1, d2, d3};
        }
        __syncthreads();
        cur = nxt;
    };

    // h0 = tanh(pre[0][row]); exchange as m=1
    float h;
    {
        float p0 = preF32 ? pre32[row_glob] : (float)__builtin_bit_cast(f16, pre16[row_glob]);
        h = fast_tanh(p0);
    }
    pushx(h);
    float tprev = tarr[0];

#pragma unroll 1
    for (int i = 1; i < T_LEN; ++i) {
        float tc  = tarr[i];
        float dtt = tc - tprev; tprev = tc;
        float dt  = 0.25f * dtt;            // N_SUB = 4
        float hdt = 0.5f * dt;
        float sixth = dt * (1.f / 6.f);
        float pv = preF32 ? pre32[(size_t)i * HID + row_glob]
                          : (float)__builtin_bit_cast(f16, pre16[(size_t)i * HID + row_glob]);
#pragma unroll 1
        for (int sub = 0; sub < 4; ++sub) {
            float ks = 0.f;
#pragma unroll 1
            for (int s = 0; s < 4; ++s) {
                float z = mv_ode();
                float k = fast_tanh(z + bo);
                float wk = (s == 1 || s == 2) ? 2.f : 1.f;
                ks = fmaf(wk, k, ks);
                float n;
                if (s == 3) { h = fmaf(sixth, ks, h); n = h; }
                else        { float a = (s == 2) ? dt : hdt; n = fmaf(a, k, h); }
                pushx(n);
            }
        }
        float zh = mv_wh();
        h = fast_tanh(pv + zh);
        pushx(h);
    }

    // decode: block 0 reads full h (f16) from vbuf[cur]
    if (c == 0 && t < OUT_D) {
        float a = b_dec[t];
#pragma unroll 4
        for (int k = 0; k < HID; ++k) {
            uint16_t hb = vbuf[cur][(k >> 6) * 72 + (k & 63)];
            a = fmaf(W_dec[t * HID + k], (float)__builtin_bit_cast(f16, hb), a);
        }
        out[t] = a;
    }
}

// ---------------------------------------------------------------------------
extern "C" void kernel_launch(void* const* d_in, const int* in_sizes, int n_in,
                              void* d_out, int out_size, void* d_ws, size_t ws_size,
                              hipStream_t stream) {
    const float* tarr  = (const float*)d_in[0];
    const float* x     = (const float*)d_in[1];
    const float* W_in  = (const float*)d_in[2];
    const float* b_in  = (const float*)d_in[3];
    const float* W_h   = (const float*)d_in[4];
    const float* b_h   = (const float*)d_in[5];
    const float* W_ode = (const float*)d_in[6];
    const float* b_ode = (const float*)d_in[7];
    const float* W_dec = (const float*)d_in[8];
    const float* b_dec = (const float*)d_in[9];
    float* out = (float*)d_out;

    uint8_t*  ws       = (uint8_t*)d_ws;
    uint32_t* ode_prep = (uint32_t*)(ws);                       // 512 KB (4x128KB)
    uint32_t* wh_prep  = (uint32_t*)(ws + (512u << 10));        // 512 KB
    uint32_t* vx       = (uint32_t*)(ws + (1u << 20));          // 2 KB exchange data
    uint32_t* vflag    = (uint32_t*)(ws + (1u << 20) + 8192);   // 2 KB flags (64B-strided)
    void*     pre      = (void*)(ws + (1u << 20) + 65536);      // 64 MB f32 or 32 MB f16

    size_t need32 = (1u << 20) + 65536 + (size_t)T_LEN * HID * 4 + 4096;
    int preF32 = (ws_size >= need32) ? 1 : 0;

    hipMemsetAsync(vflag, 0, 2048, stream);   // replay-safe flag reset
    hipLaunchKernelGGL(k_prep, dim3(8), dim3(NT), 0, stream, W_ode, W_h, ode_prep, wh_prep);
    hipLaunchKernelGGL(k_pre,  dim3(1024), dim3(512), 0, stream, x, W_in, b_in, b_h,
                       (float*)pre, (uint16_t*)pre, preF32);
    hipLaunchKernelGGL(k_scan, dim3(NBLK), dim3(NT), 0, stream, ode_prep, wh_prep,
                       (const float*)pre, (const uint16_t*)pre, preF32,
                       tarr, b_ode, W_dec, b_dec, vx, vflag, out);
}